// Round 9
// baseline (163.065 us; speedup 1.0000x reference)
//
#include <hip/hip_runtime.h>

// Problem constants
#define N_ROWS 131072    // 32*4096
#define D 64
#define K_CODES 1024

typedef _Float16 f16x8 __attribute__((ext_vector_type(8)));
typedef float    f32x4 __attribute__((ext_vector_type(4)));

#define MFMA16(a, b, c) __builtin_amdgcn_mfma_f32_16x16x32_f16((a), (b), (c), 0, 0, 0)

// ---------------------------------------------------------------------------
// ws layout: csqr[1024] f32 (4 KB) | CBf: 16384 f16x8 units (256 KB)
// 16x16x32 fragment order. CBf unit index = tile*256 + f*64 + lane,
// f in {0:hi k0-31, 1:hi k32-63, 2:lo k0-31, 3:lo k32-63}; unit holds the
// 8 halves lane needs for that MFMA B fragment:
// B[k=(lane>>4)*8+j][n=lane&15], code = tile*16 + n.
// CBf stores the hi/lo split of (-2*c); dist = |c|^2 + x.(-2c).
// (Correctness-verified rounds 2-5, 7, 8.)
// ---------------------------------------------------------------------------
__global__ __launch_bounds__(256)
void prep_kernel(const float* __restrict__ CB, _Float16* __restrict__ CBf,
                 float* __restrict__ csqr, float* __restrict__ loss) {
    const int b = blockIdx.x, t = threadIdx.x;
    if (b < 64) {
        const int unit = b * 256 + t;
        const int tile = unit >> 8;
        const int f    = (unit >> 6) & 3;
        const int lane = unit & 63;
        const int quad = lane >> 4, lrow = lane & 15;
        const int code = tile * 16 + lrow;
        const int k0   = (f & 1) * 32 + quad * 8;
        const float* src = CB + (size_t)code * D + k0;
        float4 v0 = *(const float4*)(src);
        float4 v1 = *(const float4*)(src + 4);
        float xs[8] = {v0.x, v0.y, v0.z, v0.w, v1.x, v1.y, v1.z, v1.w};
        f16x8 o;
#pragma unroll
        for (int j = 0; j < 8; ++j) {
            float sv = -2.0f * xs[j];
            _Float16 h = (_Float16)sv;
            o[j] = (f < 2) ? h : (_Float16)(sv - (float)h);
        }
        *(f16x8*)(CBf + (size_t)unit * 8) = o;
    } else {
        if (t == 0) *loss = 0.0f;
        for (int k = t; k < K_CODES; k += 256) {
            const float4* p = (const float4*)(CB + (size_t)k * D);
            float s = 0.0f;
#pragma unroll
            for (int i = 0; i < 16; ++i) {
                float4 v = p[i];
                s += v.x * v.x + v.y * v.y + v.z * v.z + v.w * v.w;
            }
            csqr[k] = s;
        }
    }
}

// ---------------------------------------------------------------------------
// Direct global->LDS 16B copy (lane-linear dest: wave-uniform base + lane*16).
// ---------------------------------------------------------------------------
__device__ __forceinline__ void gload_lds16(const void* g, void* l) {
    __builtin_amdgcn_global_load_lds(
        (const __attribute__((address_space(1))) void*)g,
        (__attribute__((address_space(3))) void*)l,
        16, 0, 0);
}

// ---------------------------------------------------------------------------
// K1 (clean 8 waves/SIMD test, take 2): IDENTICAL to round 8 except
// __launch_bounds__(256,4). Round-8 forensics: the allocator budget is
// 256/min_waves (measured (256,2)->128, (256,3)->84, (256,4)->64,
// (256,8)->32, (512,8)->32), so min_waves=8 capped VGPR at 32 and spilled
// ~20MB each way (FETCH 41MB/WRITE 78MB). But HW occupancy needs only
// ACTUAL vgpr<=64 for 8 waves/SIMD (512-reg pool/SIMD; m69 halving at
// 64/128/256) — launch_bounds only constrains the compiler. So: compile at
// the proven-clean 64-reg point (256,4); HW then fits 8 blocks/CU via
// small LDS (16.9 KB) and grid 2048 -> 32 waves/CU = 8/SIMD.
// Block = 4 waves x 16 rows = 64 rows (MT=1); 2-buf x 2-tile LDS ring;
// csqr prefetched to regs via asm-pinned global_load_dword folded into the
// counted vmcnt: per group cs(g+1) [2] + STAGE(g+1) [2] -> vmcnt(4) retires
// cs(g)+stage(g) exactly. 2-barrier ring, split numerics (hh,hh,lh,lh,
// hl,hl; ll dropped), first-min tie-break, round-0 zq epilogue — all
// correctness-verified in round 8 (passed, absmax unchanged).
// ---------------------------------------------------------------------------
__global__ __launch_bounds__(256, 4)
void argmin_kernel(const float* __restrict__ X,
                   const _Float16* __restrict__ CBf,
                   const float* __restrict__ csqr,
                   const float* __restrict__ CB,
                   float* __restrict__ out) {
    __shared__ _Float16 Bring[2][2][2048];   // 2 bufs x 2 tiles x 4 KB
    __shared__ int   ivfin[64];
    __shared__ float lsum[4];

    const int t    = threadIdx.x;
    const int wave = t >> 6;
    const int lane = t & 63;
    const int quad = lane >> 4;
    const int lrow = lane & 15;
    const int R0   = blockIdx.x * 64;
    const int Rw   = R0 + wave * 16;         // this wave's 16 rows

// Stage group g (2 tiles = 512 units of 16B) into buf: 256 threads x 2.
#define STAGE(g_, buf_)                                                       \
    do {                                                                      \
        _Pragma("unroll")                                                     \
        for (int i_ = 0; i_ < 2; ++i_) {                                      \
            const int u_ = i_ * 256 + t;                                      \
            const f16x8* gp_ =                                                \
                (const f16x8*)CBf + (size_t)((g_) * 512 + u_);                \
            gload_lds16((const void*)gp_,                                     \
                        (void*)((char*)&Bring[buf_][0][0] + (size_t)u_ * 16));\
        }                                                                     \
    } while (0)

// Asm-pinned csqr prefetch: dst <- csqr[(g_*2+i_)*16 + lrow]. Inline asm so
// its vmcnt slot is program-order-pinned (compiler can't sink it past the
// counted wait and can't insert its own drain in the loop).
#define CSLOAD(dst_, g_, i_)                                                  \
    do {                                                                      \
        const float* a_ = csp + ((g_) * 2 + (i_)) * 16;                       \
        asm volatile("global_load_dword %0, %1, off"                          \
                     : "=&v"(dst_) : "v"(a_));                                \
    } while (0)

// Counted wait, data-tied to the cs regs consumed next (cannot hoist).
#define WAIT4(c0_, c1_)                                                       \
    asm volatile("s_waitcnt vmcnt(4)" : "+v"(c0_), "+v"(c1_) :: "memory")
#define WAIT0(c0_, c1_)                                                       \
    asm volatile("s_waitcnt vmcnt(0)" : "+v"(c0_), "+v"(c1_) :: "memory")

// Consume tile i_ (0/1) of group g_ with acc-init cs_: 4 ds_read_b128 +
// 6 MFMA + 4-slot argmin. Codes ascend with tile: strict < = first-min.
#define TILECOMP(g_, i_, cs_)                                                 \
    do {                                                                      \
        const f16x8* Bt_ = (const f16x8*)&Bring[(g_) & 1][i_][0] + lane;      \
        f16x8 b0 = Bt_[0], b1 = Bt_[64], b2 = Bt_[128], b3 = Bt_[192];        \
        const int c_ = ((g_) * 2 + (i_)) * 16 + lrow;                         \
        f32x4 acc = {cs_, cs_, cs_, cs_};                                     \
        acc = MFMA16(Ah[0], b0, acc);                                         \
        acc = MFMA16(Ah[1], b1, acc);                                         \
        acc = MFMA16(Al[0], b0, acc);                                         \
        acc = MFMA16(Al[1], b1, acc);                                         \
        acc = MFMA16(Ah[0], b2, acc);                                         \
        acc = MFMA16(Ah[1], b3, acc);                                         \
        _Pragma("unroll")                                                     \
        for (int r = 0; r < 4; ++r) {                                         \
            bool lt = acc[r] < bestd[r];                                      \
            bestd[r] = lt ? acc[r] : bestd[r];                                \
            besti[r] = lt ? c_ : besti[r];                                    \
        }                                                                     \
    } while (0)

// One group: issue next group's cs+stage, counted wait for current, barrier,
// consume 2 tiles, barrier (protects restage of this buffer next group).
#define BODY(g_, cur0_, cur1_, nxt0_, nxt1_, LAST_)                           \
    do {                                                                      \
        if (!(LAST_)) {                                                       \
            CSLOAD(nxt0_, (g_) + 1, 0);                                       \
            CSLOAD(nxt1_, (g_) + 1, 1);                                       \
            STAGE((g_) + 1, ((g_) + 1) & 1);                                  \
            WAIT4(cur0_, cur1_);                                              \
        } else {                                                              \
            WAIT0(cur0_, cur1_);                                              \
        }                                                                     \
        __builtin_amdgcn_s_barrier();                                         \
        __builtin_amdgcn_sched_barrier(0);                                    \
        TILECOMP(g_, 0, cur0_);                                               \
        TILECOMP(g_, 1, cur1_);                                               \
        __builtin_amdgcn_sched_barrier(0);                                    \
        __builtin_amdgcn_s_barrier();                                         \
    } while (0)

    const float* csp = csqr + lrow;

    // ---- Prologue: group 0's cs + stage in flight ASAP.
    float csA0, csA1, csB0, csB1;
    CSLOAD(csA0, 0, 0);
    CSLOAD(csA1, 0, 1);
    STAGE(0, 0);

    // ---- A fragments (MT=1): split(x) hi/lo. Lane holds
    // A[m=lrow][k=quad*8+j] for row Rw+lrow; ks covers the two k-halves.
    // Full wave covers its 16 rows x 64 cols exactly once -> xsq.
    f16x8 Ah[2], Al[2];
    float xsq = 0.0f;
    {
        const float* xr = X + (size_t)(Rw + lrow) * D;
#pragma unroll
        for (int ks = 0; ks < 2; ++ks) {
            const int k0 = ks * 32 + quad * 8;
            float4 v0 = *(const float4*)(xr + k0);
            float4 v1 = *(const float4*)(xr + k0 + 4);
            float xs[8] = {v0.x, v0.y, v0.z, v0.w, v1.x, v1.y, v1.z, v1.w};
            f16x8 h, l;
#pragma unroll
            for (int j = 0; j < 8; ++j) {
                xsq += xs[j] * xs[j];
                _Float16 hh = (_Float16)xs[j];
                h[j] = hh;
                l[j] = (_Float16)(xs[j] - (float)hh);
            }
            Ah[ks] = h;
            Al[ks] = l;
        }
    }

    float bestd[4];
    int   besti[4];
#pragma unroll
    for (int r = 0; r < 4; ++r) { bestd[r] = 3.0e38f; besti[r] = 0; }

    // ---- Main loop: 32 groups x 2 tiles, even/odd unrolled for static cs
    // reg naming (rule #20). First body's WAIT4+barrier also covers the
    // prologue stage (retires cs(0), stage(0), and the A loads).
    for (int g2 = 0; g2 < 30; g2 += 2) {
        BODY(g2,     csA0, csA1, csB0, csB1, false);
        BODY(g2 + 1, csB0, csB1, csA0, csA1, false);
    }
    BODY(30, csA0, csA1, csB0, csB1, false);
    BODY(31, csB0, csB1, csA0, csA1, true);

    // ---- Finalize: 16-lane column reduce (lexicographic on exact ties);
    // lrow==0 lanes hold rows Rw + quad*4 + r (C layout: row = quad*4 + r,
    // col = lrow — verified rounds 0-8).
    float dvsum = 0.0f;
#pragma unroll
    for (int r = 0; r < 4; ++r) {
        float dv = bestd[r];
        int   iv = besti[r];
#pragma unroll
        for (int m = 1; m < 16; m <<= 1) {
            float od = __shfl_xor(dv, m, 64);
            int   oi = __shfl_xor(iv, m, 64);
            if (od < dv || (od == dv && oi < iv)) { dv = od; iv = oi; }
        }
        if (lrow == 0) {
            const int rl = wave * 16 + quad * 4 + r;            // 0..63
            ivfin[rl] = iv;
            out[1 + (size_t)N_ROWS * D + R0 + rl] = (float)iv;  // idxf
            dvsum += dv;
        }
    }

    // ---- Loss partial: xsq (all lanes) + dvsum (lrow==0 lanes) reduce.
    {
        float s = xsq + dvsum;
#pragma unroll
        for (int m = 1; m < 64; m <<= 1) s += __shfl_xor(s, m, 64);
        if (lane == 0) lsum[wave] = s;
    }
    __syncthreads();                             // ivfin + lsum ready

    const float scale = 1.25f / (float)((size_t)N_ROWS * D);
    if (t == 0)
        atomicAdd(out, (lsum[0] + lsum[1] + lsum[2] + lsum[3]) * scale);

    // ---- Block-cooperative zq span write: dwords [R0*64, R0*64+4096) at
    // out+1. Global dword offset 1+R0*64+j is 16B-aligned iff j%4==3.
    float* p = out + 1 + (size_t)R0 * D;
#pragma unroll
    for (int i = 0; i < 4; ++i) {
        int q = i * 256 + t;        // 0..1023
        int j = 4 * q + 3;          // 3,7,...,4095
        if (q < 1023) {
            float v[4];
#pragma unroll
            for (int e = 0; e < 4; ++e) {
                int jj = j + e;     // may straddle a row boundary
                v[e] = CB[(size_t)ivfin[jj >> 6] * D + (jj & 63)];
            }
            *(float4*)(p + j) = make_float4(v[0], v[1], v[2], v[3]);
        } else if (q == 1023) {
            p[4095] = CB[(size_t)ivfin[63] * D + 63];
        }
    }
    if (t == 0) {   // head dwords j=0..2 (row 0, cols 0..2)
        const float* c0 = CB + (size_t)ivfin[0] * D;
        p[0] = c0[0];
        p[1] = c0[1];
        p[2] = c0[2];
    }
}

// ---------------------------------------------------------------------------
extern "C" void kernel_launch(void* const* d_in, const int* in_sizes, int n_in,
                              void* d_out, int out_size, void* d_ws,
                              size_t ws_size, hipStream_t stream) {
    const float* X  = (const float*)d_in[0];   // inputs  [131072,64]
    const float* CB = (const float*)d_in[1];   // codebook [1024,64]

    float*    csqr = (float*)d_ws;                      // 4 KB
    _Float16* CBf  = (_Float16*)((char*)d_ws + 4096);   // 256 KB

    hipLaunchKernelGGL(prep_kernel, dim3(65), dim3(256), 0, stream,
                       CB, CBf, csqr, (float*)d_out);
    hipLaunchKernelGGL(argmin_kernel, dim3(N_ROWS / 64), dim3(256), 0, stream,
                       X, CBf, csqr, CB, (float*)d_out);
}

// Round 10
// 142.848 us; speedup vs baseline: 1.1415x; 1.1415x over previous
//
#include <hip/hip_runtime.h>

// Problem constants
#define N_ROWS 131072    // 32*4096
#define D 64
#define K_CODES 1024

typedef _Float16 f16x8 __attribute__((ext_vector_type(8)));
typedef float    f32x4 __attribute__((ext_vector_type(4)));

#define MFMA16(a, b, c) __builtin_amdgcn_mfma_f32_16x16x32_f16((a), (b), (c), 0, 0, 0)

// ---------------------------------------------------------------------------
// ws layout: csqr[1024] f32 (4 KB) | CBf: 16384 f16x8 units (256 KB)
// 16x16x32 fragment order. CBf unit index = tile*256 + f*64 + lane,
// f in {0:hi k0-31, 1:hi k32-63, 2:lo k0-31, 3:lo k32-63}; unit holds the
// 8 halves lane needs for that MFMA B fragment:
// B[k=(lane>>4)*8+j][n=lane&15], code = tile*16 + n.
// CBf stores the hi/lo split of (-2*c); dist = |c|^2 + x.(-2c).
// (Correctness-verified rounds 2-5, 7-9.)
// ---------------------------------------------------------------------------
__global__ __launch_bounds__(256)
void prep_kernel(const float* __restrict__ CB, _Float16* __restrict__ CBf,
                 float* __restrict__ csqr, float* __restrict__ loss) {
    const int b = blockIdx.x, t = threadIdx.x;
    if (b < 64) {
        const int unit = b * 256 + t;
        const int tile = unit >> 8;
        const int f    = (unit >> 6) & 3;
        const int lane = unit & 63;
        const int quad = lane >> 4, lrow = lane & 15;
        const int code = tile * 16 + lrow;
        const int k0   = (f & 1) * 32 + quad * 8;
        const float* src = CB + (size_t)code * D + k0;
        float4 v0 = *(const float4*)(src);
        float4 v1 = *(const float4*)(src + 4);
        float xs[8] = {v0.x, v0.y, v0.z, v0.w, v1.x, v1.y, v1.z, v1.w};
        f16x8 o;
#pragma unroll
        for (int j = 0; j < 8; ++j) {
            float sv = -2.0f * xs[j];
            _Float16 h = (_Float16)sv;
            o[j] = (f < 2) ? h : (_Float16)(sv - (float)h);
        }
        *(f16x8*)(CBf + (size_t)unit * 8) = o;
    } else {
        if (t == 0) *loss = 0.0f;
        for (int k = t; k < K_CODES; k += 256) {
            const float4* p = (const float4*)(CB + (size_t)k * D);
            float s = 0.0f;
#pragma unroll
            for (int i = 0; i < 16; ++i) {
                float4 v = p[i];
                s += v.x * v.x + v.y * v.y + v.z * v.z + v.w * v.w;
            }
            csqr[k] = s;
        }
    }
}

// ---------------------------------------------------------------------------
// Direct global->LDS 16B copy (lane-linear dest: wave-uniform base + lane*16).
// ---------------------------------------------------------------------------
__device__ __forceinline__ void gload_lds16(const void* g, void* l) {
    __builtin_amdgcn_global_load_lds(
        (const __attribute__((address_space(1))) void*)g,
        (__attribute__((address_space(3))) void*)l,
        16, 0, 0);
}

// ---------------------------------------------------------------------------
// K1 (4-pass amortized staging): R3/R9 forensics — every {stage+vmcnt+
// barrier} unit costs ~1.3-1.5k cyc regardless of content (R3: 16 units/
// 128 rows = 63.7us; R9: 32 units/64 rows = 88us; all between-barrier
// scheduling nulls, m233 concurs). Fix: AMORTIZE. Block = 8 waves x 32 rows
// (MT=2) = 256 rows; kernel = 4 PASSES; pass p stages codes [256p,+256)
// (64 KB, whole-tile single buffer) then waves FREE-RUN 16 tiles x 12 MFMA
// with zero barriers inside the pass. Per block: 8 barriers + 4 stages for
// 256 rows = 8-16x less sync overhead per row than R3. Staging traffic
// halves (512 blocks x 256KB). Per-CU per-pass: MFMA 14.9k cyc > LDS-read
// 12.3k -> compute-bound. LDS 69 KB -> 2 blocks/CU; grid 512 = 2/CU;
// 16 waves/CU = 4/SIMD at the proven-clean 64-reg point (512,4).
// Fragment layouts, split numerics (hh,hh,lh,lh,hl,hl; ll dropped), acc-
// init=csqr, first-min tie-break (codes ascend with (p,tile): strict <;
// 16-lane column reduce index-lexicographic), zq epilogue — all verbatim
// from the correctness-verified rounds (scaled to 256 rows).
// ---------------------------------------------------------------------------
__global__ __launch_bounds__(512, 4)
void argmin_kernel(const float* __restrict__ X,
                   const _Float16* __restrict__ CBf,
                   const float* __restrict__ csqr,
                   const float* __restrict__ CB,
                   float* __restrict__ out) {
    __shared__ _Float16 Bbuf[16][2048];   // 64 KB: 16 tiles x 4 KB (one pass)
    __shared__ float LsC[K_CODES];        // csqr copy, 4 KB
    __shared__ int   ivfin[256];
    __shared__ float lsum[8];

    const int t    = threadIdx.x;         // 0..511
    const int wave = t >> 6;              // 0..7
    const int lane = t & 63;
    const int quad = lane >> 4;
    const int lrow = lane & 15;
    const int R0   = blockIdx.x * 256;
    const int Rw   = R0 + wave * 32;      // this wave's 32 rows

// Stage pass p (16 tiles = 4096 units of 16B): 512 threads x 8 gload_lds.
// u_local = i*512 + t -> wave-uniform base + lane*16 (lane-linear dest).
#define STAGE(p_)                                                             \
    do {                                                                      \
        _Pragma("unroll")                                                     \
        for (int i_ = 0; i_ < 8; ++i_) {                                      \
            const int u_ = i_ * 512 + t;                                      \
            const f16x8* gp_ =                                                \
                (const f16x8*)CBf + (size_t)((p_) * 4096 + u_);               \
            gload_lds16((const void*)gp_,                                     \
                        (void*)((char*)&Bbuf[0][0] + (size_t)u_ * 16));       \
        }                                                                     \
    } while (0)

    STAGE(0);                          // pass-0 B in flight ASAP

    // csqr -> LDS (covered by the prologue __syncthreads).
    if (t < 256) ((float4*)LsC)[t] = ((const float4*)csqr)[t];

    // ---- A fragments (MT=2): split(x) hi/lo. Lane holds
    // A[m=lrow][k=quad*8+j] for rows Rw+mt*16+lrow; quads x ks cover the 64
    // columns -> per-wave xsq counts each of its 32x64 elements once.
    f16x8 Ah[2][2], Al[2][2];
    float xsq = 0.0f;
#pragma unroll
    for (int mt = 0; mt < 2; ++mt) {
        const float* xr = X + (size_t)(Rw + mt * 16 + lrow) * D;
#pragma unroll
        for (int ks = 0; ks < 2; ++ks) {
            const int k0 = ks * 32 + quad * 8;
            float4 v0 = *(const float4*)(xr + k0);
            float4 v1 = *(const float4*)(xr + k0 + 4);
            float xs[8] = {v0.x, v0.y, v0.z, v0.w, v1.x, v1.y, v1.z, v1.w};
            f16x8 h, l;
#pragma unroll
            for (int j = 0; j < 8; ++j) {
                xsq += xs[j] * xs[j];
                _Float16 hh = (_Float16)xs[j];
                h[j] = hh;
                l[j] = (_Float16)(xs[j] - (float)hh);
            }
            Ah[mt][ks] = h;
            Al[mt][ks] = l;
        }
    }

    float bestd[2][4];
    int   besti[2][4];
#pragma unroll
    for (int mt = 0; mt < 2; ++mt)
#pragma unroll
        for (int r = 0; r < 4; ++r) { bestd[mt][r] = 3.0e38f; besti[mt][r] = 0; }

    __syncthreads();   // pass-0 B + LsC + A ready (full drain, prologue)

    // ---- 4 passes x 16 tiles. No barriers inside a pass: waves free-run;
    // compiler pipelines ds_read <-> MFMA with fine-grained lgkmcnt.
    for (int p = 0; p < 4; ++p) {
        if (p) {
            __syncthreads();           // all waves done reading pass p-1
            STAGE(p);
            asm volatile("s_waitcnt vmcnt(0)" ::: "memory");
            __syncthreads();           // pass-p B visible to all waves
        }
#pragma unroll 4
        for (int i = 0; i < 16; ++i) {
            const f16x8* Bt = (const f16x8*)&Bbuf[i][0] + lane;
            f16x8 b0 = Bt[0], b1 = Bt[64], b2 = Bt[128], b3 = Bt[192];
            const int   c  = (p * 16 + i) * 16 + lrow;
            const float cs = LsC[c];
#pragma unroll
            for (int mt = 0; mt < 2; ++mt) {
                f32x4 acc = {cs, cs, cs, cs};
                acc = MFMA16(Ah[mt][0], b0, acc);
                acc = MFMA16(Ah[mt][1], b1, acc);
                acc = MFMA16(Al[mt][0], b0, acc);
                acc = MFMA16(Al[mt][1], b1, acc);
                acc = MFMA16(Ah[mt][0], b2, acc);
                acc = MFMA16(Ah[mt][1], b3, acc);
#pragma unroll
                for (int r = 0; r < 4; ++r) {
                    bool lt = acc[r] < bestd[mt][r];
                    bestd[mt][r] = lt ? acc[r] : bestd[mt][r];
                    besti[mt][r] = lt ? c : besti[mt][r];
                }
            }
        }
    }

    // ---- Finalize: 16-lane column reduce (lexicographic on exact ties);
    // lrow==0 lanes hold rows Rw + mt*16 + quad*4 + r (C layout:
    // row = quad*4 + r, col = lrow — verified rounds 0-9).
    float dvsum = 0.0f;
#pragma unroll
    for (int mt = 0; mt < 2; ++mt) {
#pragma unroll
        for (int r = 0; r < 4; ++r) {
            float dv = bestd[mt][r];
            int   iv = besti[mt][r];
#pragma unroll
            for (int m = 1; m < 16; m <<= 1) {
                float od = __shfl_xor(dv, m, 64);
                int   oi = __shfl_xor(iv, m, 64);
                if (od < dv || (od == dv && oi < iv)) { dv = od; iv = oi; }
            }
            if (lrow == 0) {
                const int rl = wave * 32 + mt * 16 + quad * 4 + r;  // 0..255
                ivfin[rl] = iv;
                out[1 + (size_t)N_ROWS * D + R0 + rl] = (float)iv;  // idxf
                dvsum += dv;
            }
        }
    }

    // ---- Loss partial: xsq (all lanes) + dvsum (lrow==0 lanes) reduce.
    {
        float s = xsq + dvsum;
#pragma unroll
        for (int m = 1; m < 64; m <<= 1) s += __shfl_xor(s, m, 64);
        if (lane == 0) lsum[wave] = s;
    }
    __syncthreads();                             // ivfin + lsum ready

    const float scale = 1.25f / (float)((size_t)N_ROWS * D);
    if (t == 0) {
        float L = 0.0f;
#pragma unroll
        for (int w = 0; w < 8; ++w) L += lsum[w];
        atomicAdd(out, L * scale);
    }

    // ---- Block-cooperative zq span write: dwords [R0*64, R0*64+16384) at
    // out+1. Global dword offset 1+R0*64+j is 16B-aligned iff j%4==3.
    float* p = out + 1 + (size_t)R0 * D;
#pragma unroll
    for (int i = 0; i < 8; ++i) {
        int q = i * 512 + t;        // 0..4095
        int j = 4 * q + 3;          // 3,7,...,16383
        if (q < 4095) {
            float v[4];
#pragma unroll
            for (int e = 0; e < 4; ++e) {
                int jj = j + e;     // may straddle a row boundary
                v[e] = CB[(size_t)ivfin[jj >> 6] * D + (jj & 63)];
            }
            *(float4*)(p + j) = make_float4(v[0], v[1], v[2], v[3]);
        } else if (q == 4095) {
            p[16383] = CB[(size_t)ivfin[255] * D + 63];
        }
    }
    if (t == 0) {   // head dwords j=0..2 (row 0, cols 0..2)
        const float* c0 = CB + (size_t)ivfin[0] * D;
        p[0] = c0[0];
        p[1] = c0[1];
        p[2] = c0[2];
    }
}

// ---------------------------------------------------------------------------
extern "C" void kernel_launch(void* const* d_in, const int* in_sizes, int n_in,
                              void* d_out, int out_size, void* d_ws,
                              size_t ws_size, hipStream_t stream) {
    const float* X  = (const float*)d_in[0];   // inputs  [131072,64]
    const float* CB = (const float*)d_in[1];   // codebook [1024,64]

    float*    csqr = (float*)d_ws;                      // 4 KB
    _Float16* CBf  = (_Float16*)((char*)d_ws + 4096);   // 256 KB

    hipLaunchKernelGGL(prep_kernel, dim3(65), dim3(256), 0, stream,
                       CB, CBf, csqr, (float*)d_out);
    hipLaunchKernelGGL(argmin_kernel, dim3(N_ROWS / 256), dim3(512), 0, stream,
                       X, CBf, csqr, CB, (float*)d_out);
}